// Round 5
// baseline (403.385 us; speedup 1.0000x reference)
//
#include <hip/hip_runtime.h>

#define AS1 __attribute__((address_space(1)))
#define AS3 __attribute__((address_space(3)))

using u16 = unsigned short;
using u32 = unsigned int;
typedef __attribute__((ext_vector_type(8))) short bf16x8;
typedef __attribute__((ext_vector_type(4))) float f32x4;

constexpr int Bn    = 32;
constexpr int Tn    = 16384;
constexpr int TCn   = 16364;   // Tn - (K-1)
constexpr int TILE  = 256;     // conv block t-tile (64 tiles exactly)
constexpr int XROWS = 280;     // staged rows per conv block
constexpr int TPAD  = 16416;   // Tn + 32 zero pad rows
constexpr int SPPCH = 64;      // spp chunks per batch row (256 rows each)

__device__ __forceinline__ u16 f2bf(float f) {
  union { float f; u32 u; } v; v.f = f;
  u32 u = v.u;
  u += 0x7fffu + ((u >> 16) & 1u);   // RNE
  return (u16)(u >> 16);
}
__device__ __forceinline__ float bf2f(u32 h) {
  union { u32 u; float f; } v; v.u = h << 16; return v.f;
}
// order-preserving float<->uint (monotone: max(encf a, encf b) = encf(max(a,b)))
__device__ __forceinline__ u32 encf(float f) {
  union { float f; u32 u; } v; v.f = f;
  return (v.u & 0x80000000u) ? ~v.u : (v.u | 0x80000000u);
}
__device__ __forceinline__ float decf(u32 u) {
  union { u32 u; float f; } v;
  v.u = (u & 0x80000000u) ? (u ^ 0x80000000u) : ~u;
  return v.f;
}
__device__ __forceinline__ void gload_lds16(const void* g, void* l) {
  __builtin_amdgcn_global_load_lds((const AS1 u32*)g, (AS3 u32*)l, 16, 0, 0);
}
__device__ __forceinline__ float leaky(float z) { return z > 0.f ? z : 0.01f * z; }

// ---------------------------------------------------------------------------
// Kernel 1: (a) x -> x_t[b][t][ci ^ ((t&7)*8)] bf16 + zero pad; (b) weight
// repack into MFMA A-fragment order. UNCHANGED from the measured rounds.
// ---------------------------------------------------------------------------
__global__ __launch_bounds__(256) void transpose_x(const float* __restrict__ x,
                                                   u16* __restrict__ x_t,
                                                   const float* __restrict__ w1,
                                                   const float* __restrict__ w2,
                                                   u16* __restrict__ wf1,
                                                   u16* __restrict__ wf2) {
  __shared__ u16 lt[64][64];               // 8 KB, [t][ci] (plain)
  const int bx  = blockIdx.x;
  const int tid = threadIdx.x;

  if (bx >= Bn * 256) {                    // ---- weight repack (84 blocks) ----
    const int bxx = bx - Bn * 256;
    const int cv  = bxx / 42;
    const int c   = bxx % 42;
    const float* w = cv ? w2 : w1;
    u16* wf = cv ? wf2 : wf1;
    const int ct   = tid >> 6;
    const int lane = tid & 63;
    const int q  = lane >> 4;
    const int rr = lane & 15;
    const int k  = c >> 1;
    const int cb = (c & 1) * 32;
    const int co = ct * 16 + rr;
    u16 us[8] __attribute__((aligned(16)));
#pragma unroll
    for (int j = 0; j < 8; ++j) {
      int ci = cb + q * 8 + j;
      us[j] = f2bf(w[((size_t)co * 64 + ci) * 21 + k]);
    }
    *(uint4*)&wf[((size_t)(c * 4 + ct) * 64 + lane) * 8] = *(const uint4*)us;
    return;
  }

  const int b   = bx >> 8;
  const int tt  = bx & 255;
  const int t0  = tt * 64;
  const int ci0 = (tid & 15) * 4;
  const int tl0 = (tid >> 4) * 4;
  float4 v[4];
#pragma unroll
  for (int j = 0; j < 4; ++j)
    v[j] = *(const float4*)(x + (size_t)(b * 64 + ci0 + j) * Tn + t0 + tl0);
  float vr[4][4] = {{v[0].x,v[0].y,v[0].z,v[0].w},{v[1].x,v[1].y,v[1].z,v[1].w},
                    {v[2].x,v[2].y,v[2].z,v[2].w},{v[3].x,v[3].y,v[3].z,v[3].w}};
#pragma unroll
  for (int e = 0; e < 4; ++e) {
    int tl = tl0 + e;
    u32 lo = (u32)f2bf(vr[0][e]) | ((u32)f2bf(vr[1][e]) << 16);
    u32 hi = (u32)f2bf(vr[2][e]) | ((u32)f2bf(vr[3][e]) << 16);
    uint2 pk = make_uint2(lo, hi);
    *(uint2*)&lt[tl][ci0] = pk;              // ds_write_b64, PLAIN index
  }
  __syncthreads();
  const int row = tid >> 2;
  const int seg = tid & 3;
  const int c0  = seg * 16;
  const int sw  = (row & 7) * 8;
  u16* op = x_t + ((size_t)b * TPAD + t0 + row) * 64 + c0;
  *(uint4*)op       = *(const uint4*)&lt[row][c0 ^ sw];        // swizzle on READ
  *(uint4*)(op + 8) = *(const uint4*)&lt[row][(c0 + 8) ^ sw];
  if (tt == 0) {
    uint4 z = make_uint4(0u, 0u, 0u, 0u);
    uint4* pz = (uint4*)(x_t + ((size_t)b * TPAD + Tn) * 64);
    pz[tid] = z;
  }
}

// ---------------------------------------------------------------------------
// Kernel 2: implicit-GEMM conv, CV-FUSED barrier-free K-loop.
// Round-4 diagnosis: the K-loop is LDS-read-pipe-bound (per CU per c-iter:
// 16 waves x 4 ds_read_b128 x ~12cy = 768 cy on the one LDS pipe vs 310 cy
// of matrix work per SIMD). Fix: one block computes BOTH conv branches —
// each bx LDS read now feeds 32 MFMAs (16 w1 + 16 w2) instead of 16, and
// x_t is staged ONCE (FETCH_SIZE should halve to ~41 MB). Grid halves to
// 2048 blocks; acc doubles (accA/accB) -> ~220 reg/wave, 2 waves/SIMD
// (__launch_bounds__(256,2)); LDS (36.9 KB) allows 2 blocks/CU = 8 waves/CU.
// ---------------------------------------------------------------------------
__global__ __launch_bounds__(256, 2) void conv_mfma(const u16* __restrict__ x_t,
                                                    const u16* __restrict__ wf1,
                                                    const u16* __restrict__ wf2,
                                                    u16* __restrict__ y1,
                                                    u16* __restrict__ y2,
                                                    float* __restrict__ stats) {
  __shared__ u16 xs[XROWS * 64];       // 35,840 B
  __shared__ float sred[256];          // 1024 B -> total 36,864 B

  const int bid  = blockIdx.x;
  const int tile = bid & 63;
  const int b    = bid >> 6;
  const int t0   = tile * TILE;
  const int tid  = threadIdx.x;
  const int w    = tid >> 6;    // wave id
  const int lane = tid & 63;
  const int q    = lane >> 4;
  const int r    = lane & 15;

  sred[tid] = 0.f;

  // stage x tile once for both branches: 280 rows * 128B = 35 x 1KB chunks
  const u16* xg = x_t + ((size_t)b * TPAD + t0) * 64;
  for (int s = w; s < 35; s += 4)
    gload_lds16(xg + (size_t)s * 512 + lane * 8, &xs[s * 512]);

  // per-thread weight fragment pointers: frag (c,ct) at wf + c*2048 + ct*512
  const u16* w1l = wf1 + lane * 8;
  const u16* w2l = wf2 + lane * 8;
  bf16x8 afA1[4], afA2[4], afB1[4], afB2[4];
#pragma unroll
  for (int ct = 0; ct < 4; ++ct) {
    afA1[ct] = *(const bf16x8*)(w1l + ct * 512);           // cv0, c=0
    afA2[ct] = *(const bf16x8*)(w2l + ct * 512);           // cv1, c=0
    afB1[ct] = *(const bf16x8*)(w1l + 2048 + ct * 512);    // cv0, c=1
    afB2[ct] = *(const bf16x8*)(w2l + 2048 + ct * 512);    // cv1, c=1
  }

  __syncthreads();   // x tile + sred init visible; drains once, before loop

  f32x4 accA[4][4], accB[4][4];
#pragma unroll
  for (int a = 0; a < 4; ++a)
#pragma unroll
    for (int t = 0; t < 4; ++t) {
      accA[a][t] = (f32x4){0.f, 0.f, 0.f, 0.f};
      accB[a][t] = (f32x4){0.f, 0.f, 0.f, 0.f};
    }

  const int rowbase = w * 64 + r;

  for (int j = 0; j < 21; ++j) {
    // both phases of pair j share k = j; swizzle line is tt-invariant
    const int swl  = ((rowbase + j) & 7) * 8;
    const int cid0 = (q * 8) ^ swl;          // phase A: cb = 0
    const int cid1 = cid0 ^ 32;              // phase B: cb = 32
    // ---- phase A: c = 2j ----
    {
      bf16x8 bx[4];
#pragma unroll
      for (int tt = 0; tt < 4; ++tt)
        bx[tt] = *(const bf16x8*)&xs[(rowbase + tt * 16 + j) * 64 + cid0];
      __builtin_amdgcn_s_setprio(1);
#pragma unroll
      for (int ct = 0; ct < 4; ++ct)
#pragma unroll
        for (int tt = 0; tt < 4; ++tt) {
          accA[ct][tt] = __builtin_amdgcn_mfma_f32_16x16x32_bf16(afA1[ct], bx[tt], accA[ct][tt], 0, 0, 0);
          accB[ct][tt] = __builtin_amdgcn_mfma_f32_16x16x32_bf16(afA2[ct], bx[tt], accB[ct][tt], 0, 0, 0);
        }
      __builtin_amdgcn_s_setprio(0);
      if (j < 20) {
        const u16* p1 = w1l + (size_t)(2 * j + 2) * 2048;
        const u16* p2 = w2l + (size_t)(2 * j + 2) * 2048;
#pragma unroll
        for (int ct = 0; ct < 4; ++ct) {
          afA1[ct] = *(const bf16x8*)(p1 + ct * 512);
          afA2[ct] = *(const bf16x8*)(p2 + ct * 512);
        }
      }
    }
    // ---- phase B: c = 2j+1 ----
    {
      bf16x8 bx[4];
#pragma unroll
      for (int tt = 0; tt < 4; ++tt)
        bx[tt] = *(const bf16x8*)&xs[(rowbase + tt * 16 + j) * 64 + cid1];
      __builtin_amdgcn_s_setprio(1);
#pragma unroll
      for (int ct = 0; ct < 4; ++ct)
#pragma unroll
        for (int tt = 0; tt < 4; ++tt) {
          accA[ct][tt] = __builtin_amdgcn_mfma_f32_16x16x32_bf16(afB1[ct], bx[tt], accA[ct][tt], 0, 0, 0);
          accB[ct][tt] = __builtin_amdgcn_mfma_f32_16x16x32_bf16(afB2[ct], bx[tt], accB[ct][tt], 0, 0, 0);
        }
      __builtin_amdgcn_s_setprio(0);
      if (j < 20) {
        const u16* p1 = w1l + (size_t)(2 * j + 3) * 2048;
        const u16* p2 = w2l + (size_t)(2 * j + 3) * 2048;
#pragma unroll
        for (int ct = 0; ct < 4; ++ct) {
          afB1[ct] = *(const bf16x8*)(p1 + ct * 512);
          afB2[ct] = *(const bf16x8*)(p2 + ct * 512);
        }
      }
    }
  }

  // ---- BN statistics for both branches (mask t >= TCn; only tile 63) ----
  const bool full_t = (t0 + TILE <= TCn);
  auto bnstats = [&](f32x4 (&acc)[4][4], int base) {
#pragma unroll
    for (int ct = 0; ct < 4; ++ct)
#pragma unroll
      for (int i = 0; i < 4; ++i) {
        float sv = 0.f, sq = 0.f;
        if (full_t) {
#pragma unroll
          for (int tt = 0; tt < 4; ++tt) {
            float v = acc[ct][tt][i];
            sv += v; sq += v * v;
          }
        } else {
#pragma unroll
          for (int tt = 0; tt < 4; ++tt) {
            int tg = t0 + w * 64 + tt * 16 + r;
            if (tg < TCn) {
              float v = acc[ct][tt][i];
              sv += v; sq += v * v;
            }
          }
        }
#pragma unroll
        for (int m = 1; m < 16; m <<= 1) {
          sv += __shfl_xor(sv, m, 64);
          sq += __shfl_xor(sq, m, 64);
        }
        if (r == 0) {
          int co = ct * 16 + q * 4 + i;
          atomicAdd(&sred[base + co * 2], sv);
          atomicAdd(&sred[base + co * 2 + 1], sq);
        }
      }
  };
  bnstats(accA, 0);
  bnstats(accB, 128);

  __syncthreads();   // all waves done reading xs before reuse as y staging

  // ---- store y_t[b][t][co] via LDS transpose (reuse xs), XOR-swizzled ----
  u16* ys = xs;
  auto writeYs = [&](f32x4 (&acc)[4][4]) {
#pragma unroll
    for (int ct = 0; ct < 4; ++ct)
#pragma unroll
      for (int tt = 0; tt < 4; ++tt) {
        int tl = w * 64 + tt * 16 + r;
        int sw = (tl & 7) * 8;
        int co0 = (ct * 16 + q * 4) ^ sw;    // XOR hits bits 3-5: stays 4-aligned
        u32 lo = (u32)f2bf(acc[ct][tt][0]) | ((u32)f2bf(acc[ct][tt][1]) << 16);
        u32 hi = (u32)f2bf(acc[ct][tt][2]) | ((u32)f2bf(acc[ct][tt][3]) << 16);
        *(uint2*)&ys[tl * 64 + co0] = make_uint2(lo, hi);
      }
  };
  auto storeYo = [&](u16* yo) {
#pragma unroll
    for (int m = 0; m < 8; ++m) {
      int flat = m * 256 + tid;
      int row  = flat >> 3;
      int c0   = (flat & 7) * 8;
      int sw   = (row & 7) * 8;
      *(uint4*)(yo + (size_t)row * 64 + c0) = *(const uint4*)&ys[row * 64 + (c0 ^ sw)];
    }
  };
  writeYs(accA);
  __syncthreads();
  storeYo(y1 + ((size_t)b * Tn + t0) * 64);
  __syncthreads();
  writeYs(accB);
  __syncthreads();
  storeYo(y2 + ((size_t)b * Tn + t0) * 64);
  atomicAdd(&stats[tid], sred[tid]);
}

// ---------------------------------------------------------------------------
// Kernel 3: SPP — ATOMIC-FREE. BYTE-IDENTICAL to round-4's measured version.
// ---------------------------------------------------------------------------
__global__ __launch_bounds__(256) void spp(const u16* __restrict__ y1,
                                           const u16* __restrict__ y2,
                                           const float* __restrict__ stats,
                                           const float* __restrict__ g1v,
                                           const float* __restrict__ b1v,
                                           const float* __restrict__ g2v,
                                           const float* __restrict__ b2v,
                                           const int* __restrict__ orig_len,
                                           u32* __restrict__ part) {
  __shared__ float lred[4][16][4][5];    // 5 KB: [wave][g][j][{m1,m2,s0,sb0,sb1}]
  const int bx = blockIdx.x;
  const int b  = bx >> 6;
  const int ch = bx & 63;
  const int tid  = threadIdx.x;
  const int g    = tid & 15;       // channel group: co = g*4 .. g*4+3
  const int trow = tid >> 4;       // 0..15 (spans waves)
  const int wv   = tid >> 6;       // wave id
  const int co0  = g * 4;
  const int L     = orig_len[b] - 20;
  const int str2  = L >> 1;
  const int kern2 = L - str2;
  const float Nf = 32.0f * 16364.0f;
  float a1[4], c1[4], a2[4], c2[4];
#pragma unroll
  for (int j = 0; j < 4; ++j) {
    int co = co0 + j;
    float s, sq, mean, var;
    s = stats[co * 2]; sq = stats[co * 2 + 1];
    mean = s / Nf; var = sq / Nf - mean * mean; if (var < 0.f) var = 0.f;
    a1[j] = g1v[co] * rsqrtf(var + 1e-5f);
    c1[j] = b1v[co] - mean * a1[j];
    s = stats[128 + co * 2]; sq = stats[128 + co * 2 + 1];
    mean = s / Nf; var = sq / Nf - mean * mean; if (var < 0.f) var = 0.f;
    a2[j] = g2v[co] * rsqrtf(var + 1e-5f);
    c2[j] = b2v[co] - mean * a2[j];
  }
  float m1[4] = {-3.4e38f,-3.4e38f,-3.4e38f,-3.4e38f};
  float m2[4] = {-3.4e38f,-3.4e38f,-3.4e38f,-3.4e38f};
  float s0[4] = {0,0,0,0}, sb0[4] = {0,0,0,0}, sb1[4] = {0,0,0,0};
  const int tbase = ch * 256;
  int tend = tbase + 256;
  if (tend > L) tend = L;
  const u16* p1 = y1 + (size_t)b * Tn * 64 + co0;
  const u16* p2 = y2 + (size_t)b * Tn * 64 + co0;

  auto body = [&](int t) {
    uint2 v1 = *(const uint2*)(p1 + (size_t)t * 64);
    uint2 v2 = *(const uint2*)(p2 + (size_t)t * 64);
    float f1[4] = { bf2f(v1.x & 0xffffu), bf2f(v1.x >> 16),
                    bf2f(v1.y & 0xffffu), bf2f(v1.y >> 16) };
    float f2[4] = { bf2f(v2.x & 0xffffu), bf2f(v2.x >> 16),
                    bf2f(v2.y & 0xffffu), bf2f(v2.y >> 16) };
    bool in0 = (t < kern2), in1 = (t >= str2);   // t < L via tend
#pragma unroll
    for (int j = 0; j < 4; ++j) {
      float z1 = leaky(fmaf(a1[j], f1[j], c1[j]));
      float z2 = leaky(fmaf(a2[j], f2[j], c2[j]));
      s0[j] += z2;
      if (in0) { m1[j] = fmaxf(m1[j], z1); sb0[j] += z2; }
      if (in1) { m2[j] = fmaxf(m2[j], z1); sb1[j] += z2; }
    }
  };

  if (tend == tbase + 256) {
    // full chunk: exactly 16 iterations
#pragma unroll 4
    for (int it = 0; it < 16; ++it)
      body(tbase + trow + it * 16);
  } else {
    for (int t = tbase + trow; t < tend; t += 16)
      body(t);
  }

  // reduce across the 4 row-lanes in this wave sharing g (lane>>4)
#pragma unroll
  for (int m = 16; m <= 32; m <<= 1) {
#pragma unroll
    for (int j = 0; j < 4; ++j) {
      m1[j]  = fmaxf(m1[j], __shfl_xor(m1[j], m, 64));
      m2[j]  = fmaxf(m2[j], __shfl_xor(m2[j], m, 64));
      s0[j]  += __shfl_xor(s0[j],  m, 64);
      sb0[j] += __shfl_xor(sb0[j], m, 64);
      sb1[j] += __shfl_xor(sb1[j], m, 64);
    }
  }
  if (((tid & 63) >> 4) == 0) {          // lanes 0-15 of each wave
#pragma unroll
    for (int j = 0; j < 4; ++j) {
      lred[wv][g][j][0] = m1[j];
      lred[wv][g][j][1] = m2[j];
      lred[wv][g][j][2] = s0[j];
      lred[wv][g][j][3] = sb0[j];
      lred[wv][g][j][4] = sb1[j];
    }
  }
  __syncthreads();
  if (tid < 64) {                        // one thread per co
    const int co = tid;
    const int g2 = co >> 2, j2 = co & 3;
    float fm1 = lred[0][g2][j2][0], fm2 = lred[0][g2][j2][1];
    float fs0 = lred[0][g2][j2][2], fb0 = lred[0][g2][j2][3], fb1v_ = lred[0][g2][j2][4];
#pragma unroll
    for (int k = 1; k < 4; ++k) {
      fm1 = fmaxf(fm1, lred[k][g2][j2][0]);
      fm2 = fmaxf(fm2, lred[k][g2][j2][1]);
      fs0 += lred[k][g2][j2][2];
      fb0 += lred[k][g2][j2][3];
      fb1v_ += lred[k][g2][j2][4];
    }
    u32* pp = part + (size_t)bx * 384;
    float* pf = (float*)pp;
    u32 e1 = encf(fm1), e2 = encf(fm2);
    pp[co]              = e1 > e2 ? e1 : e2;   // level0 max = max(bin0,bin1)
    pp[64 + co * 2]     = e1;
    pp[64 + co * 2 + 1] = e2;
    pf[192 + co]         = fs0;
    pf[256 + co * 2]     = fb0;
    pf[256 + co * 2 + 1] = fb1v_;
  }
}

// ---------------------------------------------------------------------------
// Kernel 4: FC + partial reduction. BYTE-IDENTICAL to round-4's version.
// ---------------------------------------------------------------------------
__global__ __launch_bounds__(384) void fc(const u32* __restrict__ part,
                                          const int* __restrict__ orig_len,
                                          const float* __restrict__ fc_w,
                                          const float* __restrict__ fc_b,
                                          float* __restrict__ out) {
  __shared__ float r0s[6], r1s[6];
  const int b = blockIdx.x;
  const int j = threadIdx.x;           // 0..383
  const int L = orig_len[b] - 20;
  const int kern2 = L - (L >> 1);
  const u32* pb = part + (size_t)b * 64 * 384;
  float fv;
  if (j < 192) {
    u32 vmax = 0u;
    for (int c = 0; c < 64; ++c) {
      u32 v = pb[(size_t)c * 384 + j];
      vmax = v > vmax ? v : vmax;
    }
    fv = decf(vmax);
  } else {
    const float* pf = (const float*)pb;
    float s = 0.f;
    for (int c = 0; c < 64; ++c) s += pf[(size_t)c * 384 + j];
    fv = (j < 256) ? s / (float)L : s / (float)kern2;
  }
  float a0 = fv * fc_w[j];
  float a1 = fv * fc_w[384 + j];
#pragma unroll
  for (int m = 1; m < 64; m <<= 1) {
    a0 += __shfl_xor(a0, m, 64);
    a1 += __shfl_xor(a1, m, 64);
  }
  const int wv = j >> 6, ln = j & 63;
  if (ln == 0) { r0s[wv] = a0; r1s[wv] = a1; }
  __syncthreads();
  if (j == 0) {
    float t0 = 0.f, t1 = 0.f;
#pragma unroll
    for (int k = 0; k < 6; ++k) { t0 += r0s[k]; t1 += r1s[k]; }
    out[b * 2]     = t0 + fc_b[0];
    out[b * 2 + 1] = t1 + fc_b[1];
  }
}

// ---------------------------------------------------------------------------
extern "C" void kernel_launch(void* const* d_in, const int* in_sizes, int n_in,
                              void* d_out, int out_size, void* d_ws, size_t ws_size,
                              hipStream_t stream) {
  const float* x        = (const float*)d_in[0];
  const int*   orig_len = (const int*)d_in[1];
  const float* w1  = (const float*)d_in[2];
  const float* g1  = (const float*)d_in[3];
  const float* b1  = (const float*)d_in[4];
  const float* w2  = (const float*)d_in[5];
  const float* g2  = (const float*)d_in[6];
  const float* b2  = (const float*)d_in[7];
  const float* fcw = (const float*)d_in[8];
  const float* fcb = (const float*)d_in[9];
  float* out = (float*)d_out;

  char* ws = (char*)d_ws;
  const size_t XT_BYTES = (size_t)Bn * TPAD * 64 * 2;    // 67,239,936
  const size_t Y_BYTES  = (size_t)Bn * Tn * 64 * 2;      // 67,108,864
  const size_t WF_BYTES = (size_t)42 * 4 * 64 * 8 * 2;   // 172,032
  size_t off = 0;
  u16* x_t = (u16*)(ws + off); off += XT_BYTES;
  u16* y1  = (u16*)(ws + off); off += Y_BYTES;
  u16* y2  = (u16*)(ws + off); off += Y_BYTES;
  u16* wf1 = (u16*)(ws + off); off += WF_BYTES;
  u16* wf2 = (u16*)(ws + off); off += WF_BYTES;
  float* stats = (float*)(ws + off);                 // 1024 B (2cv x 64co x {s,sq})
  u32*   part  = (u32*)(ws + off + 1024);            // 2048 * 384 * 4 = 3,145,728 B

  hipMemsetAsync(stats, 0, 1024, stream);            // partials need no memset
  transpose_x<<<Bn * 256 + 84, 256, 0, stream>>>(x, x_t, w1, w2, wf1, wf2);
  conv_mfma<<<Bn * 64, 256, 0, stream>>>(x_t, wf1, wf2, y1, y2, stats);
  spp<<<Bn * SPPCH, 256, 0, stream>>>(y1, y2, stats, g1, b1, g2, b2, orig_len, part);
  fc<<<Bn, 384, 0, stream>>>(part, orig_len, fcw, fcb, out);
  (void)in_sizes; (void)n_in; (void)out_size; (void)ws_size;
}

// Round 6
// 390.036 us; speedup vs baseline: 1.0342x; 1.0342x over previous
//
#include <hip/hip_runtime.h>

#define AS1 __attribute__((address_space(1)))
#define AS3 __attribute__((address_space(3)))

using u16 = unsigned short;
using u32 = unsigned int;
typedef __attribute__((ext_vector_type(8))) short bf16x8;
typedef __attribute__((ext_vector_type(4))) float f32x4;

constexpr int Bn    = 32;
constexpr int Tn    = 16384;
constexpr int TCn   = 16364;   // Tn - (K-1)
constexpr int TILE  = 256;     // conv block t-tile (64 tiles exactly)
constexpr int XROWS = 280;     // staged rows per conv block
constexpr int TPAD  = 16416;   // Tn + 32 zero pad rows
constexpr int SPPCH = 64;      // spp chunks per batch row (256 rows each)

__device__ __forceinline__ u16 f2bf(float f) {
  union { float f; u32 u; } v; v.f = f;
  u32 u = v.u;
  u += 0x7fffu + ((u >> 16) & 1u);   // RNE
  return (u16)(u >> 16);
}
__device__ __forceinline__ float bf2f(u32 h) {
  union { u32 u; float f; } v; v.u = h << 16; return v.f;
}
// order-preserving float<->uint (monotone: max(encf a, encf b) = encf(max(a,b)))
__device__ __forceinline__ u32 encf(float f) {
  union { float f; u32 u; } v; v.f = f;
  return (v.u & 0x80000000u) ? ~v.u : (v.u | 0x80000000u);
}
__device__ __forceinline__ float decf(u32 u) {
  union { u32 u; float f; } v;
  v.u = (u & 0x80000000u) ? (u ^ 0x80000000u) : ~u;
  return v.f;
}
__device__ __forceinline__ void gload_lds16(const void* g, void* l) {
  __builtin_amdgcn_global_load_lds((const AS1 u32*)g, (AS3 u32*)l, 16, 0, 0);
}
__device__ __forceinline__ float leaky(float z) { return z > 0.f ? z : 0.01f * z; }

// ---------------------------------------------------------------------------
// Kernel 1: (a) x -> x_t[b][t][ci ^ ((t&7)*8)] bf16 + zero pad; (b) weight
// repack into MFMA A-fragment order. UNCHANGED from the measured rounds.
// ---------------------------------------------------------------------------
__global__ __launch_bounds__(256) void transpose_x(const float* __restrict__ x,
                                                   u16* __restrict__ x_t,
                                                   const float* __restrict__ w1,
                                                   const float* __restrict__ w2,
                                                   u16* __restrict__ wf1,
                                                   u16* __restrict__ wf2) {
  __shared__ u16 lt[64][64];               // 8 KB, [t][ci] (plain)
  const int bx  = blockIdx.x;
  const int tid = threadIdx.x;

  if (bx >= Bn * 256) {                    // ---- weight repack (84 blocks) ----
    const int bxx = bx - Bn * 256;
    const int cv  = bxx / 42;
    const int c   = bxx % 42;
    const float* w = cv ? w2 : w1;
    u16* wf = cv ? wf2 : wf1;
    const int ct   = tid >> 6;
    const int lane = tid & 63;
    const int q  = lane >> 4;
    const int rr = lane & 15;
    const int k  = c >> 1;
    const int cb = (c & 1) * 32;
    const int co = ct * 16 + rr;
    u16 us[8] __attribute__((aligned(16)));
#pragma unroll
    for (int j = 0; j < 8; ++j) {
      int ci = cb + q * 8 + j;
      us[j] = f2bf(w[((size_t)co * 64 + ci) * 21 + k]);
    }
    *(uint4*)&wf[((size_t)(c * 4 + ct) * 64 + lane) * 8] = *(const uint4*)us;
    return;
  }

  const int b   = bx >> 8;
  const int tt  = bx & 255;
  const int t0  = tt * 64;
  const int ci0 = (tid & 15) * 4;
  const int tl0 = (tid >> 4) * 4;
  float4 v[4];
#pragma unroll
  for (int j = 0; j < 4; ++j)
    v[j] = *(const float4*)(x + (size_t)(b * 64 + ci0 + j) * Tn + t0 + tl0);
  float vr[4][4] = {{v[0].x,v[0].y,v[0].z,v[0].w},{v[1].x,v[1].y,v[1].z,v[1].w},
                    {v[2].x,v[2].y,v[2].z,v[2].w},{v[3].x,v[3].y,v[3].z,v[3].w}};
#pragma unroll
  for (int e = 0; e < 4; ++e) {
    int tl = tl0 + e;
    u32 lo = (u32)f2bf(vr[0][e]) | ((u32)f2bf(vr[1][e]) << 16);
    u32 hi = (u32)f2bf(vr[2][e]) | ((u32)f2bf(vr[3][e]) << 16);
    uint2 pk = make_uint2(lo, hi);
    *(uint2*)&lt[tl][ci0] = pk;              // ds_write_b64, PLAIN index
  }
  __syncthreads();
  const int row = tid >> 2;
  const int seg = tid & 3;
  const int c0  = seg * 16;
  const int sw  = (row & 7) * 8;
  u16* op = x_t + ((size_t)b * TPAD + t0 + row) * 64 + c0;
  *(uint4*)op       = *(const uint4*)&lt[row][c0 ^ sw];        // swizzle on READ
  *(uint4*)(op + 8) = *(const uint4*)&lt[row][(c0 + 8) ^ sw];
  if (tt == 0) {
    uint4 z = make_uint4(0u, 0u, 0u, 0u);
    uint4* pz = (uint4*)(x_t + ((size_t)b * TPAD + Tn) * 64);
    pz[tid] = z;
  }
}

// ---------------------------------------------------------------------------
// Kernel 2: implicit-GEMM conv — R4 structure (separate cv, barrier-free)
// with DOUBLE-DEPTH af prefetch.
// R5 post-mortem: R4/R5 are latency-stall-bound, not pipe-bound (LDS 33%,
// matrix 55%, VMEM 17% busy). af load-to-use was ~1 phase (~120 cyc) vs L2
// latency 200-300 cyc, and the 4 waves/SIMD stall near-lockstep. Fix: 4 live
// af sets (A0/B0/A1/B1, static names, hand-unrolled x2 over j) -> load-to-use
// = 3 phase clusters (~250-300 cyc). Cost: ~+32 VGPR -> 3 waves/SIMD
// (__launch_bounds__(256,3), 12 waves/CU).
// ---------------------------------------------------------------------------
__global__ __launch_bounds__(256, 3) void conv_mfma(const u16* __restrict__ x_t,
                                                    const u16* __restrict__ wf1,
                                                    const u16* __restrict__ wf2,
                                                    u16* __restrict__ y1,
                                                    u16* __restrict__ y2,
                                                    float* __restrict__ stats) {
  __shared__ u16 xs[XROWS * 64];       // 35,840 B
  __shared__ float sred[128];          // 512 B -> total 36,352 B

  const int bid  = blockIdx.x;
  const int cv   = bid & 1;
  const int tmp  = bid >> 1;
  const int tile = tmp & 63;
  const int b    = tmp >> 6;
  const int t0   = tile * TILE;
  const int tid  = threadIdx.x;
  const int w    = tid >> 6;    // wave id
  const int lane = tid & 63;
  const int q    = lane >> 4;
  const int r    = lane & 15;
  const u16* wf  = cv ? wf2 : wf1;

  if (tid < 128) sred[tid] = 0.f;

  // stage x tile: 280 rows * 128B = 35 x 1KB chunks
  const u16* xg = x_t + ((size_t)b * TPAD + t0) * 64;
  for (int s = w; s < 35; s += 4)
    gload_lds16(xg + (size_t)s * 512 + lane * 8, &xs[s * 512]);

  // per-thread weight fragment base: frag (c,ct) at wf + c*2048 + ct*512 (+lane*8)
  const u16* wfl = wf + lane * 8;
  bf16x8 afA0[4], afB0[4], afA1[4], afB1[4];
#pragma unroll
  for (int ct = 0; ct < 4; ++ct) {
    afA0[ct] = *(const bf16x8*)(wfl + (size_t)0 * 2048 + ct * 512);   // c=0
    afB0[ct] = *(const bf16x8*)(wfl + (size_t)1 * 2048 + ct * 512);   // c=1
    afA1[ct] = *(const bf16x8*)(wfl + (size_t)2 * 2048 + ct * 512);   // c=2
    afB1[ct] = *(const bf16x8*)(wfl + (size_t)3 * 2048 + ct * 512);   // c=3
  }

  __syncthreads();   // x tile (and sred init) visible; drains once, before loop

  f32x4 acc[4][4];
#pragma unroll
  for (int a = 0; a < 4; ++a)
#pragma unroll
    for (int t = 0; t < 4; ++t)
      acc[a][t] = (f32x4){0.f, 0.f, 0.f, 0.f};

  const int rowbase = w * 64 + r;

  // one MFMA phase: tap k, channel-half cb, frag set af
  auto phase = [&](const bf16x8 (&af)[4], int k, int cb) {
    const int swl = ((rowbase + k) & 7) * 8;
    const int cid = (cb + q * 8) ^ swl;
    bf16x8 bx[4];
#pragma unroll
    for (int tt = 0; tt < 4; ++tt)
      bx[tt] = *(const bf16x8*)&xs[(rowbase + tt * 16 + k) * 64 + cid];
    __builtin_amdgcn_s_setprio(1);
#pragma unroll
    for (int ct = 0; ct < 4; ++ct)
#pragma unroll
      for (int tt = 0; tt < 4; ++tt)
        acc[ct][tt] = __builtin_amdgcn_mfma_f32_16x16x32_bf16(af[ct], bx[tt], acc[ct][tt], 0, 0, 0);
    __builtin_amdgcn_s_setprio(0);
  };
  auto loadaf = [&](bf16x8 (&af)[4], int c) {
    const u16* p = wfl + (size_t)c * 2048;
#pragma unroll
    for (int ct = 0; ct < 4; ++ct) af[ct] = *(const bf16x8*)(p + ct * 512);
  };

  // c = 4*ii + {0,1,2,3}; each set reloaded 3 phase-clusters before next use
  for (int ii = 0; ii < 10; ++ii) {
    const int k0 = 2 * ii, k1 = 2 * ii + 1;
    phase(afA0, k0, 0);  loadaf(afA0, 4 * ii + 4);
    phase(afB0, k0, 32); loadaf(afB0, 4 * ii + 5);
    phase(afA1, k1, 0);  if (ii < 9) loadaf(afA1, 4 * ii + 6);
    phase(afB1, k1, 32); if (ii < 9) loadaf(afB1, 4 * ii + 7);
  }
  phase(afA0, 20, 0);    // c=40
  phase(afB0, 20, 32);   // c=41

  // ---- BN statistics (mask t >= TCn; only tile 63 needs the mask) ----
  const bool full_t = (t0 + TILE <= TCn);
#pragma unroll
  for (int ct = 0; ct < 4; ++ct)
#pragma unroll
    for (int i = 0; i < 4; ++i) {
      float sv = 0.f, sq = 0.f;
      if (full_t) {
#pragma unroll
        for (int tt = 0; tt < 4; ++tt) {
          float v = acc[ct][tt][i];
          sv += v; sq += v * v;
        }
      } else {
#pragma unroll
        for (int tt = 0; tt < 4; ++tt) {
          int tg = t0 + w * 64 + tt * 16 + r;
          if (tg < TCn) {
            float v = acc[ct][tt][i];
            sv += v; sq += v * v;
          }
        }
      }
#pragma unroll
      for (int m = 1; m < 16; m <<= 1) {
        sv += __shfl_xor(sv, m, 64);
        sq += __shfl_xor(sq, m, 64);
      }
      if (r == 0) {
        int co = ct * 16 + q * 4 + i;
        atomicAdd(&sred[co * 2], sv);
        atomicAdd(&sred[co * 2 + 1], sq);
      }
    }

  __syncthreads();   // all waves done reading xs before reuse as y staging

  // ---- store y_t[b][t][co] via LDS transpose (reuse xs), XOR-swizzled ----
  u16* ys = xs;
#pragma unroll
  for (int ct = 0; ct < 4; ++ct)
#pragma unroll
    for (int tt = 0; tt < 4; ++tt) {
      int tl = w * 64 + tt * 16 + r;
      int sw = (tl & 7) * 8;
      int co0 = (ct * 16 + q * 4) ^ sw;        // XOR hits bits 3-5: stays 4-aligned
      u32 lo = (u32)f2bf(acc[ct][tt][0]) | ((u32)f2bf(acc[ct][tt][1]) << 16);
      u32 hi = (u32)f2bf(acc[ct][tt][2]) | ((u32)f2bf(acc[ct][tt][3]) << 16);
      *(uint2*)&ys[tl * 64 + co0] = make_uint2(lo, hi);
    }
  __syncthreads();
  u16* yo = (cv ? y2 : y1) + ((size_t)b * Tn + t0) * 64;
#pragma unroll
  for (int m = 0; m < 8; ++m) {
    int flat = m * 256 + tid;
    int row  = flat >> 3;
    int c0   = (flat & 7) * 8;
    int sw   = (row & 7) * 8;
    *(uint4*)(yo + (size_t)row * 64 + c0) = *(const uint4*)&ys[row * 64 + (c0 ^ sw)];
  }
  if (tid < 128) atomicAdd(&stats[cv * 128 + tid], sred[tid]);
}

// ---------------------------------------------------------------------------
// Kernel 3: SPP — ATOMIC-FREE. BYTE-IDENTICAL to round-4's measured version.
// ---------------------------------------------------------------------------
__global__ __launch_bounds__(256) void spp(const u16* __restrict__ y1,
                                           const u16* __restrict__ y2,
                                           const float* __restrict__ stats,
                                           const float* __restrict__ g1v,
                                           const float* __restrict__ b1v,
                                           const float* __restrict__ g2v,
                                           const float* __restrict__ b2v,
                                           const int* __restrict__ orig_len,
                                           u32* __restrict__ part) {
  __shared__ float lred[4][16][4][5];    // 5 KB: [wave][g][j][{m1,m2,s0,sb0,sb1}]
  const int bx = blockIdx.x;
  const int b  = bx >> 6;
  const int ch = bx & 63;
  const int tid  = threadIdx.x;
  const int g    = tid & 15;       // channel group: co = g*4 .. g*4+3
  const int trow = tid >> 4;       // 0..15 (spans waves)
  const int wv   = tid >> 6;       // wave id
  const int co0  = g * 4;
  const int L     = orig_len[b] - 20;
  const int str2  = L >> 1;
  const int kern2 = L - str2;
  const float Nf = 32.0f * 16364.0f;
  float a1[4], c1[4], a2[4], c2[4];
#pragma unroll
  for (int j = 0; j < 4; ++j) {
    int co = co0 + j;
    float s, sq, mean, var;
    s = stats[co * 2]; sq = stats[co * 2 + 1];
    mean = s / Nf; var = sq / Nf - mean * mean; if (var < 0.f) var = 0.f;
    a1[j] = g1v[co] * rsqrtf(var + 1e-5f);
    c1[j] = b1v[co] - mean * a1[j];
    s = stats[128 + co * 2]; sq = stats[128 + co * 2 + 1];
    mean = s / Nf; var = sq / Nf - mean * mean; if (var < 0.f) var = 0.f;
    a2[j] = g2v[co] * rsqrtf(var + 1e-5f);
    c2[j] = b2v[co] - mean * a2[j];
  }
  float m1[4] = {-3.4e38f,-3.4e38f,-3.4e38f,-3.4e38f};
  float m2[4] = {-3.4e38f,-3.4e38f,-3.4e38f,-3.4e38f};
  float s0[4] = {0,0,0,0}, sb0[4] = {0,0,0,0}, sb1[4] = {0,0,0,0};
  const int tbase = ch * 256;
  int tend = tbase + 256;
  if (tend > L) tend = L;
  const u16* p1 = y1 + (size_t)b * Tn * 64 + co0;
  const u16* p2 = y2 + (size_t)b * Tn * 64 + co0;

  auto body = [&](int t) {
    uint2 v1 = *(const uint2*)(p1 + (size_t)t * 64);
    uint2 v2 = *(const uint2*)(p2 + (size_t)t * 64);
    float f1[4] = { bf2f(v1.x & 0xffffu), bf2f(v1.x >> 16),
                    bf2f(v1.y & 0xffffu), bf2f(v1.y >> 16) };
    float f2[4] = { bf2f(v2.x & 0xffffu), bf2f(v2.x >> 16),
                    bf2f(v2.y & 0xffffu), bf2f(v2.y >> 16) };
    bool in0 = (t < kern2), in1 = (t >= str2);   // t < L via tend
#pragma unroll
    for (int j = 0; j < 4; ++j) {
      float z1 = leaky(fmaf(a1[j], f1[j], c1[j]));
      float z2 = leaky(fmaf(a2[j], f2[j], c2[j]));
      s0[j] += z2;
      if (in0) { m1[j] = fmaxf(m1[j], z1); sb0[j] += z2; }
      if (in1) { m2[j] = fmaxf(m2[j], z1); sb1[j] += z2; }
    }
  };

  if (tend == tbase + 256) {
    // full chunk: exactly 16 iterations
#pragma unroll 4
    for (int it = 0; it < 16; ++it)
      body(tbase + trow + it * 16);
  } else {
    for (int t = tbase + trow; t < tend; t += 16)
      body(t);
  }

  // reduce across the 4 row-lanes in this wave sharing g (lane>>4)
#pragma unroll
  for (int m = 16; m <= 32; m <<= 1) {
#pragma unroll
    for (int j = 0; j < 4; ++j) {
      m1[j]  = fmaxf(m1[j], __shfl_xor(m1[j], m, 64));
      m2[j]  = fmaxf(m2[j], __shfl_xor(m2[j], m, 64));
      s0[j]  += __shfl_xor(s0[j],  m, 64);
      sb0[j] += __shfl_xor(sb0[j], m, 64);
      sb1[j] += __shfl_xor(sb1[j], m, 64);
    }
  }
  if (((tid & 63) >> 4) == 0) {          // lanes 0-15 of each wave
#pragma unroll
    for (int j = 0; j < 4; ++j) {
      lred[wv][g][j][0] = m1[j];
      lred[wv][g][j][1] = m2[j];
      lred[wv][g][j][2] = s0[j];
      lred[wv][g][j][3] = sb0[j];
      lred[wv][g][j][4] = sb1[j];
    }
  }
  __syncthreads();
  if (tid < 64) {                        // one thread per co
    const int co = tid;
    const int g2 = co >> 2, j2 = co & 3;
    float fm1 = lred[0][g2][j2][0], fm2 = lred[0][g2][j2][1];
    float fs0 = lred[0][g2][j2][2], fb0 = lred[0][g2][j2][3], fb1v_ = lred[0][g2][j2][4];
#pragma unroll
    for (int k = 1; k < 4; ++k) {
      fm1 = fmaxf(fm1, lred[k][g2][j2][0]);
      fm2 = fmaxf(fm2, lred[k][g2][j2][1]);
      fs0 += lred[k][g2][j2][2];
      fb0 += lred[k][g2][j2][3];
      fb1v_ += lred[k][g2][j2][4];
    }
    u32* pp = part + (size_t)bx * 384;
    float* pf = (float*)pp;
    u32 e1 = encf(fm1), e2 = encf(fm2);
    pp[co]              = e1 > e2 ? e1 : e2;   // level0 max = max(bin0,bin1)
    pp[64 + co * 2]     = e1;
    pp[64 + co * 2 + 1] = e2;
    pf[192 + co]         = fs0;
    pf[256 + co * 2]     = fb0;
    pf[256 + co * 2 + 1] = fb1v_;
  }
}

// ---------------------------------------------------------------------------
// Kernel 4: FC + partial reduction. BYTE-IDENTICAL to round-4's version.
// ---------------------------------------------------------------------------
__global__ __launch_bounds__(384) void fc(const u32* __restrict__ part,
                                          const int* __restrict__ orig_len,
                                          const float* __restrict__ fc_w,
                                          const float* __restrict__ fc_b,
                                          float* __restrict__ out) {
  __shared__ float r0s[6], r1s[6];
  const int b = blockIdx.x;
  const int j = threadIdx.x;           // 0..383
  const int L = orig_len[b] - 20;
  const int kern2 = L - (L >> 1);
  const u32* pb = part + (size_t)b * 64 * 384;
  float fv;
  if (j < 192) {
    u32 vmax = 0u;
    for (int c = 0; c < 64; ++c) {
      u32 v = pb[(size_t)c * 384 + j];
      vmax = v > vmax ? v : vmax;
    }
    fv = decf(vmax);
  } else {
    const float* pf = (const float*)pb;
    float s = 0.f;
    for (int c = 0; c < 64; ++c) s += pf[(size_t)c * 384 + j];
    fv = (j < 256) ? s / (float)L : s / (float)kern2;
  }
  float a0 = fv * fc_w[j];
  float a1 = fv * fc_w[384 + j];
#pragma unroll
  for (int m = 1; m < 64; m <<= 1) {
    a0 += __shfl_xor(a0, m, 64);
    a1 += __shfl_xor(a1, m, 64);
  }
  const int wv = j >> 6, ln = j & 63;
  if (ln == 0) { r0s[wv] = a0; r1s[wv] = a1; }
  __syncthreads();
  if (j == 0) {
    float t0 = 0.f, t1 = 0.f;
#pragma unroll
    for (int k = 0; k < 6; ++k) { t0 += r0s[k]; t1 += r1s[k]; }
    out[b * 2]     = t0 + fc_b[0];
    out[b * 2 + 1] = t1 + fc_b[1];
  }
}

// ---------------------------------------------------------------------------
extern "C" void kernel_launch(void* const* d_in, const int* in_sizes, int n_in,
                              void* d_out, int out_size, void* d_ws, size_t ws_size,
                              hipStream_t stream) {
  const float* x        = (const float*)d_in[0];
  const int*   orig_len = (const int*)d_in[1];
  const float* w1  = (const float*)d_in[2];
  const float* g1  = (const float*)d_in[3];
  const float* b1  = (const float*)d_in[4];
  const float* w2  = (const float*)d_in[5];
  const float* g2  = (const float*)d_in[6];
  const float* b2  = (const float*)d_in[7];
  const float* fcw = (const float*)d_in[8];
  const float* fcb = (const float*)d_in[9];
  float* out = (float*)d_out;

  char* ws = (char*)d_ws;
  const size_t XT_BYTES = (size_t)Bn * TPAD * 64 * 2;    // 67,239,936
  const size_t Y_BYTES  = (size_t)Bn * Tn * 64 * 2;      // 67,108,864
  const size_t WF_BYTES = (size_t)42 * 4 * 64 * 8 * 2;   // 172,032
  size_t off = 0;
  u16* x_t = (u16*)(ws + off); off += XT_BYTES;
  u16* y1  = (u16*)(ws + off); off += Y_BYTES;
  u16* y2  = (u16*)(ws + off); off += Y_BYTES;
  u16* wf1 = (u16*)(ws + off); off += WF_BYTES;
  u16* wf2 = (u16*)(ws + off); off += WF_BYTES;
  float* stats = (float*)(ws + off);                 // 1024 B (2cv x 64co x {s,sq})
  u32*   part  = (u32*)(ws + off + 1024);            // 2048 * 384 * 4 = 3,145,728 B

  hipMemsetAsync(stats, 0, 1024, stream);            // partials need no memset
  transpose_x<<<Bn * 256 + 84, 256, 0, stream>>>(x, x_t, w1, w2, wf1, wf2);
  conv_mfma<<<Bn * 64 * 2, 256, 0, stream>>>(x_t, wf1, wf2, y1, y2, stats);
  spp<<<Bn * SPPCH, 256, 0, stream>>>(y1, y2, stats, g1, b1, g2, b2, orig_len, part);
  fc<<<Bn, 384, 0, stream>>>(part, orig_len, fcw, fcb, out);
  (void)in_sizes; (void)n_in; (void)out_size; (void)ws_size;
}

// Round 7
// 389.681 us; speedup vs baseline: 1.0352x; 1.0009x over previous
//
#include <hip/hip_runtime.h>

#define AS1 __attribute__((address_space(1)))
#define AS3 __attribute__((address_space(3)))

using u16 = unsigned short;
using u32 = unsigned int;
typedef __attribute__((ext_vector_type(8))) short bf16x8;
typedef __attribute__((ext_vector_type(4))) float f32x4;

constexpr int Bn    = 32;
constexpr int Tn    = 16384;
constexpr int TCn   = 16364;   // Tn - (K-1)
constexpr int TILE  = 256;     // conv block t-tile (64 tiles exactly)
constexpr int XSROWS = 320;    // staged rows in LDS (5 passes of 64; >=280 used)
constexpr int SPPCH = 64;      // spp chunks per batch row (256 rows each)

__device__ __forceinline__ u16 f2bf(float f) {
  union { float f; u32 u; } v; v.f = f;
  u32 u = v.u;
  u += 0x7fffu + ((u >> 16) & 1u);   // RNE
  return (u16)(u >> 16);
}
__device__ __forceinline__ float bf2f(u32 h) {
  union { u32 u; float f; } v; v.u = h << 16; return v.f;
}
// order-preserving float<->uint (monotone: max(encf a, encf b) = encf(max(a,b)))
__device__ __forceinline__ u32 encf(float f) {
  union { float f; u32 u; } v; v.f = f;
  return (v.u & 0x80000000u) ? ~v.u : (v.u | 0x80000000u);
}
__device__ __forceinline__ float decf(u32 u) {
  union { u32 u; float f; } v;
  v.u = (u & 0x80000000u) ? (u ^ 0x80000000u) : ~u;
  return v.f;
}
__device__ __forceinline__ float leaky(float z) { return z > 0.f ? z : 0.01f * z; }

// ---------------------------------------------------------------------------
// Kernel 1: weight repack into MFMA A-fragment order (the proven branch of
// the old transpose_x; the x-transpose part is now fused into conv_mfma).
// ---------------------------------------------------------------------------
__global__ __launch_bounds__(256) void wrepack(const float* __restrict__ w1,
                                               const float* __restrict__ w2,
                                               u16* __restrict__ wf1,
                                               u16* __restrict__ wf2) {
  const int bxx = blockIdx.x;              // 0..83
  const int tid = threadIdx.x;
  const int cv  = bxx / 42;
  const int c   = bxx % 42;
  const float* w = cv ? w2 : w1;
  u16* wf = cv ? wf2 : wf1;
  const int ct   = tid >> 6;
  const int lane = tid & 63;
  const int q  = lane >> 4;
  const int rr = lane & 15;
  const int k  = c >> 1;
  const int cb = (c & 1) * 32;
  const int co = ct * 16 + rr;
  u16 us[8] __attribute__((aligned(16)));
#pragma unroll
  for (int j = 0; j < 8; ++j) {
    int ci = cb + q * 8 + j;
    us[j] = f2bf(w[((size_t)co * 64 + ci) * 21 + k]);
  }
  *(uint4*)&wf[((size_t)(c * 4 + ct) * 64 + lane) * 8] = *(const uint4*)us;
}

// ---------------------------------------------------------------------------
// Kernel 2: implicit-GEMM conv with FUSED x staging (x_t eliminated).
// Prologue stages x (f32 [b][ci][t]) -> xs bf16 [row][ci ^ ((row&7)*8)]
// directly in LDS using transpose_x's proven pack pattern (same f2bf, same
// swizzle; rows with global t >= Tn zeroed = the old x_t pad). The transpose
// VALU/LDS work now overlaps conv's idle issue slots instead of being a
// serialized 8192-block kernel + a 64MB write + 146MB read of x_t.
// K-loop/epilogue BYTE-IDENTICAL to round-6 (154 us, MfmaUtil 56%).
// ---------------------------------------------------------------------------
__global__ __launch_bounds__(256, 3) void conv_mfma(const float* __restrict__ x,
                                                    const u16* __restrict__ wf1,
                                                    const u16* __restrict__ wf2,
                                                    u16* __restrict__ y1,
                                                    u16* __restrict__ y2,
                                                    float* __restrict__ stats) {
  __shared__ u16 xs[XSROWS * 64];      // 40,960 B
  __shared__ float sred[128];          // 512 B -> total 41,472 B (3 blocks/CU)

  const int bid  = blockIdx.x;
  const int cv   = bid & 1;
  const int tmp  = bid >> 1;
  const int tile = tmp & 63;
  const int b    = tmp >> 6;
  const int t0   = tile * TILE;
  const int tid  = threadIdx.x;
  const int w    = tid >> 6;    // wave id
  const int lane = tid & 63;
  const int q    = lane >> 4;
  const int r    = lane & 15;
  const u16* wf  = cv ? wf2 : wf1;

  if (tid < 128) sred[tid] = 0.f;

  // ---- fused x staging: 5 passes of 64 rows; thread = 4 ci x 4 t ----
  const float* xb = x + (size_t)b * 64 * Tn;
  const int sci0 = (tid & 15) * 4;
  const int stl0 = (tid >> 4) * 4;
#pragma unroll
  for (int p = 0; p < 5; ++p) {
    const int row = p * 64 + stl0;         // 0..316 (step 4)
    const int gt  = t0 + row;              // global t, multiple of 4
    float4 v0, v1, v2, v3;
    if (gt < Tn) {
      const float* pb0 = xb + (size_t)sci0 * Tn + gt;
      v0 = *(const float4*)(pb0);
      v1 = *(const float4*)(pb0 + Tn);
      v2 = *(const float4*)(pb0 + 2 * Tn);
      v3 = *(const float4*)(pb0 + 3 * Tn);
    } else {
      v0 = v1 = v2 = v3 = make_float4(0.f, 0.f, 0.f, 0.f);
    }
    const float vr[4][4] = {{v0.x,v0.y,v0.z,v0.w},{v1.x,v1.y,v1.z,v1.w},
                            {v2.x,v2.y,v2.z,v2.w},{v3.x,v3.y,v3.z,v3.w}};
#pragma unroll
    for (int e = 0; e < 4; ++e) {
      int rr2 = row + e;
      int sw  = (rr2 & 7) * 8;
      u32 lo = (u32)f2bf(vr[0][e]) | ((u32)f2bf(vr[1][e]) << 16);
      u32 hi = (u32)f2bf(vr[2][e]) | ((u32)f2bf(vr[3][e]) << 16);
      *(uint2*)&xs[rr2 * 64 + (sci0 ^ sw)] = make_uint2(lo, hi);
    }
  }

  // per-thread weight fragment base: frag (c,ct) at wf + c*2048 + ct*512 (+lane*8)
  const u16* wfl = wf + lane * 8;
  bf16x8 afA0[4], afB0[4], afA1[4], afB1[4];
#pragma unroll
  for (int ct = 0; ct < 4; ++ct) {
    afA0[ct] = *(const bf16x8*)(wfl + (size_t)0 * 2048 + ct * 512);   // c=0
    afB0[ct] = *(const bf16x8*)(wfl + (size_t)1 * 2048 + ct * 512);   // c=1
    afA1[ct] = *(const bf16x8*)(wfl + (size_t)2 * 2048 + ct * 512);   // c=2
    afB1[ct] = *(const bf16x8*)(wfl + (size_t)3 * 2048 + ct * 512);   // c=3
  }

  __syncthreads();   // x tile (and sred init) visible; drains once, before loop

  f32x4 acc[4][4];
#pragma unroll
  for (int a = 0; a < 4; ++a)
#pragma unroll
    for (int t = 0; t < 4; ++t)
      acc[a][t] = (f32x4){0.f, 0.f, 0.f, 0.f};

  const int rowbase = w * 64 + r;

  // one MFMA phase: tap k, channel-half cb, frag set af
  auto phase = [&](const bf16x8 (&af)[4], int k, int cb) {
    const int swl = ((rowbase + k) & 7) * 8;
    const int cid = (cb + q * 8) ^ swl;
    bf16x8 bx[4];
#pragma unroll
    for (int tt = 0; tt < 4; ++tt)
      bx[tt] = *(const bf16x8*)&xs[(rowbase + tt * 16 + k) * 64 + cid];
    __builtin_amdgcn_s_setprio(1);
#pragma unroll
    for (int ct = 0; ct < 4; ++ct)
#pragma unroll
      for (int tt = 0; tt < 4; ++tt)
        acc[ct][tt] = __builtin_amdgcn_mfma_f32_16x16x32_bf16(af[ct], bx[tt], acc[ct][tt], 0, 0, 0);
    __builtin_amdgcn_s_setprio(0);
  };
  auto loadaf = [&](bf16x8 (&af)[4], int c) {
    const u16* p = wfl + (size_t)c * 2048;
#pragma unroll
    for (int ct = 0; ct < 4; ++ct) af[ct] = *(const bf16x8*)(p + ct * 512);
  };

  // c = 4*ii + {0,1,2,3}; each set reloaded 3 phase-clusters before next use
  for (int ii = 0; ii < 10; ++ii) {
    const int k0 = 2 * ii, k1 = 2 * ii + 1;
    phase(afA0, k0, 0);  loadaf(afA0, 4 * ii + 4);
    phase(afB0, k0, 32); loadaf(afB0, 4 * ii + 5);
    phase(afA1, k1, 0);  if (ii < 9) loadaf(afA1, 4 * ii + 6);
    phase(afB1, k1, 32); if (ii < 9) loadaf(afB1, 4 * ii + 7);
  }
  phase(afA0, 20, 0);    // c=40
  phase(afB0, 20, 32);   // c=41

  // ---- BN statistics (mask t >= TCn; only tile 63 needs the mask) ----
  const bool full_t = (t0 + TILE <= TCn);
#pragma unroll
  for (int ct = 0; ct < 4; ++ct)
#pragma unroll
    for (int i = 0; i < 4; ++i) {
      float sv = 0.f, sq = 0.f;
      if (full_t) {
#pragma unroll
        for (int tt = 0; tt < 4; ++tt) {
          float v = acc[ct][tt][i];
          sv += v; sq += v * v;
        }
      } else {
#pragma unroll
        for (int tt = 0; tt < 4; ++tt) {
          int tg = t0 + w * 64 + tt * 16 + r;
          if (tg < TCn) {
            float v = acc[ct][tt][i];
            sv += v; sq += v * v;
          }
        }
      }
#pragma unroll
      for (int m = 1; m < 16; m <<= 1) {
        sv += __shfl_xor(sv, m, 64);
        sq += __shfl_xor(sq, m, 64);
      }
      if (r == 0) {
        int co = ct * 16 + q * 4 + i;
        atomicAdd(&sred[co * 2], sv);
        atomicAdd(&sred[co * 2 + 1], sq);
      }
    }

  __syncthreads();   // all waves done reading xs before reuse as y staging

  // ---- store y_t[b][t][co] via LDS transpose (reuse xs), XOR-swizzled ----
  u16* ys = xs;
#pragma unroll
  for (int ct = 0; ct < 4; ++ct)
#pragma unroll
    for (int tt = 0; tt < 4; ++tt) {
      int tl = w * 64 + tt * 16 + r;
      int sw = (tl & 7) * 8;
      int co0 = (ct * 16 + q * 4) ^ sw;        // XOR hits bits 3-5: stays 4-aligned
      u32 lo = (u32)f2bf(acc[ct][tt][0]) | ((u32)f2bf(acc[ct][tt][1]) << 16);
      u32 hi = (u32)f2bf(acc[ct][tt][2]) | ((u32)f2bf(acc[ct][tt][3]) << 16);
      *(uint2*)&ys[tl * 64 + co0] = make_uint2(lo, hi);
    }
  __syncthreads();
  u16* yo = (cv ? y2 : y1) + ((size_t)b * Tn + t0) * 64;
#pragma unroll
  for (int m = 0; m < 8; ++m) {
    int flat = m * 256 + tid;
    int row  = flat >> 3;
    int c0   = (flat & 7) * 8;
    int sw   = (row & 7) * 8;
    *(uint4*)(yo + (size_t)row * 64 + c0) = *(const uint4*)&ys[row * 64 + (c0 ^ sw)];
  }
  if (tid < 128) atomicAdd(&stats[cv * 128 + tid], sred[tid]);
}

// ---------------------------------------------------------------------------
// Kernel 3: SPP — ATOMIC-FREE. BYTE-IDENTICAL to round-4's measured version.
// ---------------------------------------------------------------------------
__global__ __launch_bounds__(256) void spp(const u16* __restrict__ y1,
                                           const u16* __restrict__ y2,
                                           const float* __restrict__ stats,
                                           const float* __restrict__ g1v,
                                           const float* __restrict__ b1v,
                                           const float* __restrict__ g2v,
                                           const float* __restrict__ b2v,
                                           const int* __restrict__ orig_len,
                                           u32* __restrict__ part) {
  __shared__ float lred[4][16][4][5];    // 5 KB: [wave][g][j][{m1,m2,s0,sb0,sb1}]
  const int bx = blockIdx.x;
  const int b  = bx >> 6;
  const int ch = bx & 63;
  const int tid  = threadIdx.x;
  const int g    = tid & 15;       // channel group: co = g*4 .. g*4+3
  const int trow = tid >> 4;       // 0..15 (spans waves)
  const int wv   = tid >> 6;       // wave id
  const int co0  = g * 4;
  const int L     = orig_len[b] - 20;
  const int str2  = L >> 1;
  const int kern2 = L - str2;
  const float Nf = 32.0f * 16364.0f;
  float a1[4], c1[4], a2[4], c2[4];
#pragma unroll
  for (int j = 0; j < 4; ++j) {
    int co = co0 + j;
    float s, sq, mean, var;
    s = stats[co * 2]; sq = stats[co * 2 + 1];
    mean = s / Nf; var = sq / Nf - mean * mean; if (var < 0.f) var = 0.f;
    a1[j] = g1v[co] * rsqrtf(var + 1e-5f);
    c1[j] = b1v[co] - mean * a1[j];
    s = stats[128 + co * 2]; sq = stats[128 + co * 2 + 1];
    mean = s / Nf; var = sq / Nf - mean * mean; if (var < 0.f) var = 0.f;
    a2[j] = g2v[co] * rsqrtf(var + 1e-5f);
    c2[j] = b2v[co] - mean * a2[j];
  }
  float m1[4] = {-3.4e38f,-3.4e38f,-3.4e38f,-3.4e38f};
  float m2[4] = {-3.4e38f,-3.4e38f,-3.4e38f,-3.4e38f};
  float s0[4] = {0,0,0,0}, sb0[4] = {0,0,0,0}, sb1[4] = {0,0,0,0};
  const int tbase = ch * 256;
  int tend = tbase + 256;
  if (tend > L) tend = L;
  const u16* p1 = y1 + (size_t)b * Tn * 64 + co0;
  const u16* p2 = y2 + (size_t)b * Tn * 64 + co0;

  auto body = [&](int t) {
    uint2 v1 = *(const uint2*)(p1 + (size_t)t * 64);
    uint2 v2 = *(const uint2*)(p2 + (size_t)t * 64);
    float f1[4] = { bf2f(v1.x & 0xffffu), bf2f(v1.x >> 16),
                    bf2f(v1.y & 0xffffu), bf2f(v1.y >> 16) };
    float f2[4] = { bf2f(v2.x & 0xffffu), bf2f(v2.x >> 16),
                    bf2f(v2.y & 0xffffu), bf2f(v2.y >> 16) };
    bool in0 = (t < kern2), in1 = (t >= str2);   // t < L via tend
#pragma unroll
    for (int j = 0; j < 4; ++j) {
      float z1 = leaky(fmaf(a1[j], f1[j], c1[j]));
      float z2 = leaky(fmaf(a2[j], f2[j], c2[j]));
      s0[j] += z2;
      if (in0) { m1[j] = fmaxf(m1[j], z1); sb0[j] += z2; }
      if (in1) { m2[j] = fmaxf(m2[j], z1); sb1[j] += z2; }
    }
  };

  if (tend == tbase + 256) {
    // full chunk: exactly 16 iterations
#pragma unroll 4
    for (int it = 0; it < 16; ++it)
      body(tbase + trow + it * 16);
  } else {
    for (int t = tbase + trow; t < tend; t += 16)
      body(t);
  }

  // reduce across the 4 row-lanes in this wave sharing g (lane>>4)
#pragma unroll
  for (int m = 16; m <= 32; m <<= 1) {
#pragma unroll
    for (int j = 0; j < 4; ++j) {
      m1[j]  = fmaxf(m1[j], __shfl_xor(m1[j], m, 64));
      m2[j]  = fmaxf(m2[j], __shfl_xor(m2[j], m, 64));
      s0[j]  += __shfl_xor(s0[j],  m, 64);
      sb0[j] += __shfl_xor(sb0[j], m, 64);
      sb1[j] += __shfl_xor(sb1[j], m, 64);
    }
  }
  if (((tid & 63) >> 4) == 0) {          // lanes 0-15 of each wave
#pragma unroll
    for (int j = 0; j < 4; ++j) {
      lred[wv][g][j][0] = m1[j];
      lred[wv][g][j][1] = m2[j];
      lred[wv][g][j][2] = s0[j];
      lred[wv][g][j][3] = sb0[j];
      lred[wv][g][j][4] = sb1[j];
    }
  }
  __syncthreads();
  if (tid < 64) {                        // one thread per co
    const int co = tid;
    const int g2 = co >> 2, j2 = co & 3;
    float fm1 = lred[0][g2][j2][0], fm2 = lred[0][g2][j2][1];
    float fs0 = lred[0][g2][j2][2], fb0 = lred[0][g2][j2][3], fb1v_ = lred[0][g2][j2][4];
#pragma unroll
    for (int k = 1; k < 4; ++k) {
      fm1 = fmaxf(fm1, lred[k][g2][j2][0]);
      fm2 = fmaxf(fm2, lred[k][g2][j2][1]);
      fs0 += lred[k][g2][j2][2];
      fb0 += lred[k][g2][j2][3];
      fb1v_ += lred[k][g2][j2][4];
    }
    u32* pp = part + (size_t)bx * 384;
    float* pf = (float*)pp;
    u32 e1 = encf(fm1), e2 = encf(fm2);
    pp[co]              = e1 > e2 ? e1 : e2;   // level0 max = max(bin0,bin1)
    pp[64 + co * 2]     = e1;
    pp[64 + co * 2 + 1] = e2;
    pf[192 + co]         = fs0;
    pf[256 + co * 2]     = fb0;
    pf[256 + co * 2 + 1] = fb1v_;
  }
}

// ---------------------------------------------------------------------------
// Kernel 4: FC + partial reduction. BYTE-IDENTICAL to round-4's version.
// ---------------------------------------------------------------------------
__global__ __launch_bounds__(384) void fc(const u32* __restrict__ part,
                                          const int* __restrict__ orig_len,
                                          const float* __restrict__ fc_w,
                                          const float* __restrict__ fc_b,
                                          float* __restrict__ out) {
  __shared__ float r0s[6], r1s[6];
  const int b = blockIdx.x;
  const int j = threadIdx.x;           // 0..383
  const int L = orig_len[b] - 20;
  const int kern2 = L - (L >> 1);
  const u32* pb = part + (size_t)b * 64 * 384;
  float fv;
  if (j < 192) {
    u32 vmax = 0u;
    for (int c = 0; c < 64; ++c) {
      u32 v = pb[(size_t)c * 384 + j];
      vmax = v > vmax ? v : vmax;
    }
    fv = decf(vmax);
  } else {
    const float* pf = (const float*)pb;
    float s = 0.f;
    for (int c = 0; c < 64; ++c) s += pf[(size_t)c * 384 + j];
    fv = (j < 256) ? s / (float)L : s / (float)kern2;
  }
  float a0 = fv * fc_w[j];
  float a1 = fv * fc_w[384 + j];
#pragma unroll
  for (int m = 1; m < 64; m <<= 1) {
    a0 += __shfl_xor(a0, m, 64);
    a1 += __shfl_xor(a1, m, 64);
  }
  const int wv = j >> 6, ln = j & 63;
  if (ln == 0) { r0s[wv] = a0; r1s[wv] = a1; }
  __syncthreads();
  if (j == 0) {
    float t0 = 0.f, t1 = 0.f;
#pragma unroll
    for (int k = 0; k < 6; ++k) { t0 += r0s[k]; t1 += r1s[k]; }
    out[b * 2]     = t0 + fc_b[0];
    out[b * 2 + 1] = t1 + fc_b[1];
  }
}

// ---------------------------------------------------------------------------
extern "C" void kernel_launch(void* const* d_in, const int* in_sizes, int n_in,
                              void* d_out, int out_size, void* d_ws, size_t ws_size,
                              hipStream_t stream) {
  const float* x        = (const float*)d_in[0];
  const int*   orig_len = (const int*)d_in[1];
  const float* w1  = (const float*)d_in[2];
  const float* g1  = (const float*)d_in[3];
  const float* b1  = (const float*)d_in[4];
  const float* w2  = (const float*)d_in[5];
  const float* g2  = (const float*)d_in[6];
  const float* b2  = (const float*)d_in[7];
  const float* fcw = (const float*)d_in[8];
  const float* fcb = (const float*)d_in[9];
  float* out = (float*)d_out;

  char* ws = (char*)d_ws;
  const size_t Y_BYTES  = (size_t)Bn * Tn * 64 * 2;      // 67,108,864
  const size_t WF_BYTES = (size_t)42 * 4 * 64 * 8 * 2;   // 172,032
  size_t off = 0;
  u16* y1  = (u16*)(ws + off); off += Y_BYTES;
  u16* y2  = (u16*)(ws + off); off += Y_BYTES;
  u16* wf1 = (u16*)(ws + off); off += WF_BYTES;
  u16* wf2 = (u16*)(ws + off); off += WF_BYTES;
  float* stats = (float*)(ws + off);                 // 1024 B (2cv x 64co x {s,sq})
  u32*   part  = (u32*)(ws + off + 1024);            // 2048 * 384 * 4 = 3,145,728 B

  hipMemsetAsync(stats, 0, 1024, stream);            // partials need no memset
  wrepack<<<84, 256, 0, stream>>>(w1, w2, wf1, wf2);
  conv_mfma<<<Bn * 64 * 2, 256, 0, stream>>>(x, wf1, wf2, y1, y2, stats);
  spp<<<Bn * SPPCH, 256, 0, stream>>>(y1, y2, stats, g1, b1, g2, b2, orig_len, part);
  fc<<<Bn, 384, 0, stream>>>(part, orig_len, fcw, fcb, out);
  (void)in_sizes; (void)n_in; (void)out_size; (void)ws_size;
}